// Round 1
// baseline (715.267 us; speedup 1.0000x reference)
//
#include <hip/hip_runtime.h>
#include <cstdint>

#define BB 4096
#define NV 20
#define CC 512
#define HH 256   // hidden
#define NC 40    // classes
#define SV 8     // selected views
#define GG 3     // batches per block
#define TAU 2e-4f

typedef short short8 __attribute__((ext_vector_type(8)));
typedef float f32x4 __attribute__((ext_vector_type(4)));
typedef unsigned short ushort4v __attribute__((ext_vector_type(4)));

__device__ __forceinline__ unsigned short f2bf(float x) {
    unsigned u = __float_as_uint(x);
    unsigned r = (u + 0x7FFFu + ((u >> 16) & 1u)) >> 16;
    return (unsigned short)r;
}
__device__ __forceinline__ float bf2f(unsigned short h) {
    return __uint_as_float(((unsigned)h) << 16);
}

#define MFMA16(A, B, C) __builtin_amdgcn_mfma_f32_16x16x32_bf16(A, B, C, 0, 0, 0)
#define BC8(x) __builtin_bit_cast(short8, x)

// ---------------------------------------------------------------------------
// W1 [512][256] -> fragment-ordered bf16 hi/lo (same layout as before):
//   e = ((ks*256 + n)*4 + kq)*8 + j3 ; k = ks*32 + kq*8 + j3
// ---------------------------------------------------------------------------
__global__ void w1pack_kernel(const float* __restrict__ W1,
                              unsigned short* __restrict__ w1fh,
                              unsigned short* __restrict__ w1fl) {
    int e = blockIdx.x * 256 + threadIdx.x;           // 131072 total
    int j3 = e & 7, kq = (e >> 3) & 3, n = (e >> 5) & 255, ks = e >> 13;
    int k = ks * 32 + kq * 8 + j3;
    float x = W1[k * HH + n];
    unsigned short h = f2bf(x);
    w1fh[e] = h;
    w1fl[e] = f2bf(x - bf2f(h));
}

// W2 [256][40] -> padded N=48 fragment order: e = ((ks*48+n)*4+kq)*8+j3
__global__ void w2pack_kernel(const float* __restrict__ W2,
                              unsigned short* __restrict__ w2fh,
                              unsigned short* __restrict__ w2fl) {
    int e = blockIdx.x * 256 + threadIdx.x;           // 12288 total
    int j3 = e & 7, kq = (e >> 3) & 3;
    int t = e >> 5;
    int n = t % 48, ks = t / 48;
    int k = ks * 32 + kq * 8 + j3;
    float x = (n < NC) ? W2[k * NC + n] : 0.f;
    unsigned short h = f2bf(x);
    w2fh[e] = h;
    w2fl[e] = f2bf(x - bf2f(h));
}

// ---------------------------------------------------------------------------
// Fused kernel, pipelined:
//   A staging is double-buffered (one barrier per K-chunk; global loads for
//   chunk kc+2 are in flight across chunk kc's MFMA phase).
//   The pooled row no longer flows through layer-1: since layer-1 is linear,
//   its pre-activation = mean of the 20 view pre-activations, recovered from
//   the accumulators via two shfl_xor at layer-2 H-write time.
// LDS (aliased):
//   K-loop:  buf0 Ahi/Alo @0/@9216, buf1 @18432/@27648  (36864 B)
//   layer2:  Hhi[32][264] @0 (16896B), Hlo @16896 (ends 33792)
//   rescue:  pooledD[512]f64 @0, Dbuf @4096, Sd @6144, SFd @6464
//   persistent: Sc[3][840]f32 @36864 (ends 46944)
// ---------------------------------------------------------------------------
__global__ __launch_bounds__(256, 3) void fused_kernel(
    const float* __restrict__ F0, const float* __restrict__ V0,
    const float* __restrict__ W1, const float* __restrict__ b1,
    const float* __restrict__ W2, const float* __restrict__ b2,
    const unsigned short* __restrict__ w1fh, const unsigned short* __restrict__ w1fl,
    const unsigned short* __restrict__ w2fh, const unsigned short* __restrict__ w2fl,
    float* __restrict__ outF, float* __restrict__ outS, float* __restrict__ outV)
{
    const int blk = blockIdx.x;
    const int j = threadIdx.x;
    const int L = j & 63, wq = j >> 6, l15 = L & 15, kq = L >> 4;

    __shared__ __align__(16) char lds[46944];
    __shared__ int idx8[GG][SV];
    __shared__ int flags0[GG], flags1[GG], predS[GG];

    unsigned short* Ahi0 = (unsigned short*)lds;            // [64][72]
    unsigned short* Alo0 = Ahi0 + 64 * 72;                  // @9216
    unsigned short* Ahi1 = (unsigned short*)(lds + 18432);  // [64][72]
    unsigned short* Alo1 = Ahi1 + 64 * 72;                  // @27648
    unsigned short* Hhi  = (unsigned short*)lds;            // [32][264]
    unsigned short* Hlo  = Hhi + 32 * 264;                  // @16896
    float*  Sc      = (float*)(lds + 36864);                // 3*840 f32
    double* pooledD = (double*)lds;
    double* Dbuf    = (double*)(lds + 4096);
    double* Sd      = (double*)(lds + 6144);
    double* SFd     = (double*)(lds + 6464);

    // ---- layer-1 accumulators: acc[mt][nt], row g = mt*16+kq*4+reg (g<60 valid),
    //      col = wq*64 + nt*16 + l15.  Global row g -> batch g/20, view g%20.
    f32x4 acc[4][4];
#pragma unroll
    for (int mt = 0; mt < 4; ++mt)
#pragma unroll
        for (int nt = 0; nt < 4; ++nt) acc[mt][nt] = (f32x4){0.f, 0.f, 0.f, 0.f};

    // ---- per-thread staging descriptors (fixed across K-chunks) -------------
    const float4* srcp[4];
    int ldst[4];
    bool sval[4];
#pragma unroll
    for (int i = 0; i < 4; ++i) {
        int f = j + 256 * i;              // float4 slot in chunk [0,1024)
        int row = f >> 4, k4 = f & 15;
        sval[i] = (row < 60);
        int bi = (row >= 40) ? 2 : (row >= 20) ? 1 : 0;
        int r = row - 20 * bi;
        int batch = blk * GG + bi; if (batch > BB - 1) batch = BB - 1;
        srcp[i] = (const float4*)(F0 + ((size_t)batch * NV + r) * CC) + k4;
        ldst[i] = row * 72 + k4 * 4;
    }

    float4 rv[4];
    auto STAGE_LOAD = [&](int kc) {
#pragma unroll
        for (int i = 0; i < 4; ++i)
            if (sval[i]) rv[i] = srcp[i][kc * 16];
    };
    auto STAGE_CONVERT = [&](unsigned short* __restrict__ Ah,
                             unsigned short* __restrict__ Al) {
#pragma unroll
        for (int i = 0; i < 4; ++i) {
            ushort4v hv = {0, 0, 0, 0}, lv = {0, 0, 0, 0};
            if (sval[i]) {
                float4 x = rv[i];
                hv.x = f2bf(x.x); lv.x = f2bf(x.x - bf2f(hv.x));
                hv.y = f2bf(x.y); lv.y = f2bf(x.y - bf2f(hv.y));
                hv.z = f2bf(x.z); lv.z = f2bf(x.z - bf2f(hv.z));
                hv.w = f2bf(x.w); lv.w = f2bf(x.w - bf2f(hv.w));
            }
            *(ushort4v*)&Ah[ldst[i]] = hv;
            *(ushort4v*)&Al[ldst[i]] = lv;
        }
    };

    const uint4* Bh = (const uint4*)w1fh;
    const uint4* Bl = (const uint4*)w1fl;

    // ---- pipelined K-loop: 8 chunks of Kc=64, ONE barrier per chunk --------
    STAGE_LOAD(0);
    STAGE_CONVERT(Ahi0, Alo0);
    STAGE_LOAD(1);
    __syncthreads();

    unsigned short *Ahc = Ahi0, *Alc = Alo0, *Ahn = Ahi1, *Aln = Alo1;
    for (int kc = 0; kc < 8; ++kc) {
        if (kc < 7) {
            STAGE_CONVERT(Ahn, Aln);       // chunk kc+1 regs -> next buffer
            if (kc < 6) STAGE_LOAD(kc + 2);  // in flight across this MFMA phase
        }
#pragma unroll
        for (int ks_l = 0; ks_l < 2; ++ks_l) {
            int ks = kc * 2 + ks_l;
            uint4 bh[4], bl[4];
#pragma unroll
            for (int nt = 0; nt < 4; ++nt) {
                int bi1 = (ks * 256 + wq * 64 + nt * 16 + l15) * 4 + kq;
                bh[nt] = Bh[bi1]; bl[nt] = Bl[bi1];
            }
#pragma unroll
            for (int mt = 0; mt < 4; ++mt) {
                int off = (mt * 16 + l15) * 72 + ks_l * 32 + kq * 8;
                short8 Ah = BC8(*(const uint4*)&Ahc[off]);
                short8 Al = BC8(*(const uint4*)&Alc[off]);
#pragma unroll
                for (int nt = 0; nt < 4; ++nt) {
                    short8 Bhv = BC8(bh[nt]), Blv = BC8(bl[nt]);
                    acc[mt][nt] = MFMA16(Ah, Bhv, acc[mt][nt]);
                    acc[mt][nt] = MFMA16(Ah, Blv, acc[mt][nt]);
                    acc[mt][nt] = MFMA16(Al, Bhv, acc[mt][nt]);
                }
            }
        }
        __syncthreads();
        unsigned short* t;
        t = Ahc; Ahc = Ahn; Ahn = t;
        t = Alc; Alc = Aln; Aln = t;
    }

    // ---- layer 2: two rounds of 32 H-rows through LDS ----------------------
    // round p covers acc rows 32p..32p+31; in round 1, rows 28..30 of the H
    // buffer carry the 3 pooled rows (row 31 zeroed), giving Sc rows 60..62.
    const uint4* B2h = (const uint4*)w2fh;
    const uint4* B2l = (const uint4*)w2fl;
#pragma unroll
    for (int p = 0; p < 2; ++p) {
        __syncthreads();   // H region free (A reads / prev round reads done)
#pragma unroll
        for (int mt2 = 0; mt2 < 2; ++mt2) {
            int mt = 2 * p + mt2;
            bool skip = (p == 1 && mt2 == 1 && kq == 3);  // garbage rows 28..31
#pragma unroll
            for (int nt = 0; nt < 4; ++nt) {
                int col = wq * 64 + nt * 16 + l15;
                float bc = b1[col];
#pragma unroll
                for (int reg = 0; reg < 4; ++reg) {
                    int hb = mt2 * 16 + kq * 4 + reg;
                    float h = acc[mt][nt][reg] + bc;
                    h = (h > 0.f) ? h : 0.2f * h;
                    if (!skip) {
                        unsigned short hh = f2bf(h);
                        Hhi[hb * 264 + col] = hh;
                        Hlo[hb * 264 + col] = f2bf(h - bf2f(hh));
                    }
                }
            }
        }
        if (p == 1) {
            // pooled pre-activation = mean over the 20 view pre-activations
#pragma unroll
            for (int nt = 0; nt < 4; ++nt) {
                int col = wq * 64 + nt * 16 + l15;
                float p0 = 0.f, p1 = 0.f, p2 = 0.f;
#pragma unroll
                for (int mt = 0; mt < 4; ++mt)
#pragma unroll
                    for (int reg = 0; reg < 4; ++reg) {
                        int g = mt * 16 + kq * 4 + reg;
                        float v = acc[mt][nt][reg];
                        p0 += (g < 20) ? v : 0.f;
                        p1 += (g >= 20 && g < 40) ? v : 0.f;
                        p2 += (g >= 40 && g < 60) ? v : 0.f;
                    }
                p0 += __shfl_xor(p0, 16); p0 += __shfl_xor(p0, 32);
                p1 += __shfl_xor(p1, 16); p1 += __shfl_xor(p1, 32);
                p2 += __shfl_xor(p2, 16); p2 += __shfl_xor(p2, 32);
                if (kq < 3) {
                    float s = (kq == 0) ? p0 : (kq == 1) ? p1 : p2;
                    float h = s * (1.0f / NV) + b1[col];
                    h = (h > 0.f) ? h : 0.2f * h;
                    unsigned short hh = f2bf(h);
                    Hhi[(28 + kq) * 264 + col] = hh;
                    Hlo[(28 + kq) * 264 + col] = f2bf(h - bf2f(hh));
                } else {
                    Hhi[31 * 264 + col] = 0;
                    Hlo[31 * 264 + col] = 0;
                }
            }
        }
        __syncthreads();

        if (wq < 3) {
            f32x4 sacc[2];
            sacc[0] = (f32x4){0.f, 0.f, 0.f, 0.f};
            sacc[1] = (f32x4){0.f, 0.f, 0.f, 0.f};
            for (int ks2 = 0; ks2 < 8; ++ks2) {
                int bi2 = (ks2 * 48 + wq * 16 + l15) * 4 + kq;
                short8 Bhv = BC8(B2h[bi2]), Blv = BC8(B2l[bi2]);
#pragma unroll
                for (int tt = 0; tt < 2; ++tt) {
                    int off = (tt * 16 + l15) * 264 + ks2 * 32 + kq * 8;
                    short8 Ah2 = BC8(*(const uint4*)&Hhi[off]);
                    short8 Al2 = BC8(*(const uint4*)&Hlo[off]);
                    sacc[tt] = MFMA16(Ah2, Bhv, sacc[tt]);
                    sacc[tt] = MFMA16(Ah2, Blv, sacc[tt]);
                    sacc[tt] = MFMA16(Al2, Bhv, sacc[tt]);
                }
            }
            int cls = wq * 16 + l15;
            if (cls < NC) {
                float bc2 = b2[cls];
#pragma unroll
                for (int tt = 0; tt < 2; ++tt)
#pragma unroll
                    for (int reg = 0; reg < 4; ++reg) {
                        int lm = 32 * p + tt * 16 + kq * 4 + reg;
                        float sv = sacc[tt][reg] + bc2;
                        if (lm < 60) {
                            int bi = (lm >= 40) ? 2 : (lm >= 20) ? 1 : 0;
                            int r = lm - 20 * bi;
                            Sc[bi * 840 + r * NC + cls] = sv;
                        } else if (lm < 63) {
                            Sc[(lm - 60) * 840 + NV * NC + cls] = sv;  // pooled
                        }
                    }
            }
        }
    }
    __syncthreads();

    // ---- decisions: pred argmax (3 parallel lanes, gap-guarded) ------------
    if (j < GG) {
        const float* sp = &Sc[j * 840 + NV * NC];
        int p = 0;
        float m1 = sp[0];
        for (int c = 1; c < NC; ++c)
            if (sp[c] > m1) { m1 = sp[c]; p = c; }
        float m2 = -1e30f;
        for (int c = 0; c < NC; ++c)
            if (c != p && sp[c] > m2) m2 = sp[c];
        flags0[j] = (m1 - m2 < TAU) ? 1 : 0;
        predS[j] = p;
    }
    __syncthreads();

    for (int bi = 0; bi < GG; ++bi) {
        if (flags0[bi]) {   // rare: f64 rescore of pooled row
            int batch = blk * GG + bi; if (batch > BB - 1) batch = BB - 1;
            const float* Xb = F0 + (size_t)batch * (NV * CC);
            for (int c = j; c < CC; c += 256) {
                double s = 0.0;
                for (int r = 0; r < NV; ++r) s += (double)Xb[r * CC + c];
                pooledD[c] = s / (double)NV;
            }
            __syncthreads();
            double a = 0.0;
            for (int c = 0; c < CC; ++c) a += pooledD[c] * (double)W1[c * HH + j];
            double h = a + (double)b1[j];
            h = (h > 0.0) ? h : 0.2 * h;
            Dbuf[j] = h;
            __syncthreads();
            if (j < NC) {
                double s = 0.0;
                for (int k = 0; k < HH; ++k) s += Dbuf[k] * (double)W2[k * NC + j];
                Sd[j] = s + (double)b2[j];
            }
            __syncthreads();
            if (j == 0) {
                int p = 0;
                double m = Sd[0];
                for (int c = 1; c < NC; ++c)
                    if (Sd[c] > m) { m = Sd[c]; p = c; }
                predS[bi] = p;
            }
            __syncthreads();
        }
    }

    // ---- top-8 selection (3 parallel lanes, gap-guarded) -------------------
    if (j < GG) {
        int p = predS[j];
        float v[NV];
#pragma unroll
        for (int n = 0; n < NV; ++n) v[n] = Sc[j * 840 + n * NC + p];
        int ord[9];
        float vals[9];
        unsigned taken = 0;
#pragma unroll
        for (int s = 0; s < 9; ++s) {
            int bi = 0;
            float bv = -1e30f;
#pragma unroll
            for (int n = 0; n < NV; ++n)
                if (!((taken >> n) & 1u) && v[n] > bv) { bv = v[n]; bi = n; }
            taken |= 1u << bi;
            ord[s] = bi;
            vals[s] = bv;
        }
        int fix = 0;
#pragma unroll
        for (int s = 0; s < 8; ++s)
            if (vals[s] - vals[s + 1] < TAU) fix = 1;
        flags1[j] = fix;
        if (!fix)
#pragma unroll
            for (int s = 0; s < SV; ++s) idx8[j][s] = ord[s];
    }
    __syncthreads();

    for (int bi = 0; bi < GG; ++bi) {
        if (flags1[bi]) {   // rare: full f64 rescore of 20 view scores at col pred
            int batch = blk * GG + bi; if (batch > BB - 1) batch = BB - 1;
            const float* Xb = F0 + (size_t)batch * (NV * CC);
            int p = predS[bi];
            for (int r = 0; r < NV; ++r) {
                double a = 0.0;
                for (int c = 0; c < CC; ++c)
                    a += (double)Xb[r * CC + c] * (double)W1[c * HH + j];
                double h = a + (double)b1[j];
                h = (h > 0.0) ? h : 0.2 * h;
                Dbuf[j] = h * (double)W2[j * NC + p];
                __syncthreads();
                for (int off = 128; off >= 1; off >>= 1) {
                    if (j < off) Dbuf[j] += Dbuf[j + off];
                    __syncthreads();
                }
                if (j == 0) SFd[r] = Dbuf[0] + (double)b2[p];
                __syncthreads();
            }
            if (j == 0) {
                unsigned taken = 0;
                for (int s = 0; s < SV; ++s) {
                    int bsel = 0;
                    double bv = -1e300;
                    for (int n = 0; n < NV; ++n)
                        if (!((taken >> n) & 1u) && SFd[n] > bv) { bv = SFd[n]; bsel = n; }
                    taken |= 1u << bsel;
                    idx8[bi][s] = bsel;
                }
            }
            __syncthreads();
        }
    }

    // ---- epilogue -----------------------------------------------------------
    for (int t = j; t < GG * NV * NC; t += 256) {
        int bi = t / 800, o = t - bi * 800;
        int batch = blk * GG + bi; if (batch > BB - 1) batch = BB - 1;
        outS[(size_t)batch * (NV * NC) + o] = Sc[bi * 840 + o];
    }

    for (int t = j; t < GG * SV * (CC / 4); t += 256) {
        int bi = t >> 10;                 // /1024
        int s = (t >> 7) & 7;
        int t4 = t & 127;
        int batch = blk * GG + bi; if (batch > BB - 1) batch = BB - 1;
        int row = idx8[bi][s];
        const float4* src = (const float4*)(F0 + ((size_t)batch * NV + row) * CC);
        float4* dst = (float4*)(outF + ((size_t)batch * SV + s) * CC);
        dst[t4] = src[t4];
    }

    if (j < GG * SV * 3) {
        int bi = j / 24, o = j - bi * 24;
        int s = o / 3, d = o - s * 3;
        int batch = blk * GG + bi; if (batch > BB - 1) batch = BB - 1;
        outV[((size_t)batch * SV + s) * 3 + d] =
            V0[((size_t)batch * NV + idx8[bi][s]) * 3 + d];
    }
}

// ---------------------------------------------------------------------------
extern "C" void kernel_launch(void* const* d_in, const int* in_sizes, int n_in,
                              void* d_out, int out_size, void* d_ws, size_t ws_size,
                              hipStream_t stream) {
    const float* F0 = (const float*)d_in[0];
    const float* V0 = (const float*)d_in[1];
    const float* W1 = (const float*)d_in[2];
    const float* b1 = (const float*)d_in[3];
    const float* W2 = (const float*)d_in[4];
    const float* b2 = (const float*)d_in[5];

    char* ws = (char*)d_ws;
    unsigned short* w1fh = (unsigned short*)ws;                   // 262144 B
    unsigned short* w1fl = (unsigned short*)(ws + 262144);        // 262144 B
    unsigned short* w2fh = (unsigned short*)(ws + 524288);        // 24576 B
    unsigned short* w2fl = (unsigned short*)(ws + 548864);        // 24576 B

    float* out = (float*)d_out;
    float* outF = out;                                // [4096,8,512]
    float* outS = out + (size_t)BB * SV * CC;         // [4096,20,40]
    float* outV = outS + (size_t)BB * NV * NC;        // [4096,8,3]

    w1pack_kernel<<<512, 256, 0, stream>>>(W1, w1fh, w1fl);
    w2pack_kernel<<<48, 256, 0, stream>>>(W2, w2fh, w2fl);
    fused_kernel<<<(BB + GG - 1) / GG, 256, 0, stream>>>(
        F0, V0, W1, b1, W2, b2, w1fh, w1fl, w2fh, w2fl, outF, outS, outV);
}

// Round 4
// 443.109 us; speedup vs baseline: 1.6142x; 1.6142x over previous
//
#include <hip/hip_runtime.h>
#include <cstdint>

#define BB 4096
#define NV 20
#define CC 512
#define HH 256   // hidden
#define NC 40    // classes
#define SV 8     // selected views
#define GG 3     // batches per block
#define TAU 2e-4f

typedef short short8 __attribute__((ext_vector_type(8)));
typedef float f32x4 __attribute__((ext_vector_type(4)));
typedef unsigned short ushort4v __attribute__((ext_vector_type(4)));

__device__ __forceinline__ unsigned short f2bf(float x) {
    unsigned u = __float_as_uint(x);
    unsigned r = (u + 0x7FFFu + ((u >> 16) & 1u)) >> 16;
    return (unsigned short)r;
}
__device__ __forceinline__ float bf2f(unsigned short h) {
    return __uint_as_float(((unsigned)h) << 16);
}

#define MFMA16(A, B, C) __builtin_amdgcn_mfma_f32_16x16x32_bf16(A, B, C, 0, 0, 0)
#define BC8(x) __builtin_bit_cast(short8, x)

// ---------------------------------------------------------------------------
// W1 [512][256] -> fragment-ordered bf16 hi/lo (same layout as before):
//   e = ((ks*256 + n)*4 + kq)*8 + j3 ; k = ks*32 + kq*8 + j3
// ---------------------------------------------------------------------------
__global__ void w1pack_kernel(const float* __restrict__ W1,
                              unsigned short* __restrict__ w1fh,
                              unsigned short* __restrict__ w1fl) {
    int e = blockIdx.x * 256 + threadIdx.x;           // 131072 total
    int j3 = e & 7, kq = (e >> 3) & 3, n = (e >> 5) & 255, ks = e >> 13;
    int k = ks * 32 + kq * 8 + j3;
    float x = W1[k * HH + n];
    unsigned short h = f2bf(x);
    w1fh[e] = h;
    w1fl[e] = f2bf(x - bf2f(h));
}

// W2 [256][40] -> padded N=48 fragment order: e = ((ks*48+n)*4+kq)*8+j3
__global__ void w2pack_kernel(const float* __restrict__ W2,
                              unsigned short* __restrict__ w2fh,
                              unsigned short* __restrict__ w2fl) {
    int e = blockIdx.x * 256 + threadIdx.x;           // 12288 total
    int j3 = e & 7, kq = (e >> 3) & 3;
    int t = e >> 5;
    int n = t % 48, ks = t / 48;
    int k = ks * 32 + kq * 8 + j3;
    float x = (n < NC) ? W2[k * NC + n] : 0.f;
    unsigned short h = f2bf(x);
    w2fh[e] = h;
    w2fl[e] = f2bf(x - bf2f(h));
}

// ---------------------------------------------------------------------------
// Fused kernel. Main path identical to R0 (pipelined dbuf staging, pooled row
// recovered from accumulators). The flags1 f64 rescue is restructured from
// {20 serial rows x 512-iter dependent chain + 8-barrier tree per row}
// (~400k cycles) to {LDS-staged X, all 20 dots per thread concurrently,
// wave-shuffle reduction} (~60k cycles).
// LDS (aliased):
//   K-loop:  buf0 Ahi/Alo @0/@9216, buf1 @18432/@27648  (36864 B)
//   layer2:  Hhi[32][264] @0 (16896B), Hlo @16896 (ends 33792)
//   rescue0: pooledD[512]f64 @0, Dbuf @4096, Sd @6144
//   rescue1: Xf[20][512]f32 @0 (40960 B)
//   persistent: Sc[3][840]f32 @40960 (ends 51040)
// ---------------------------------------------------------------------------
__global__ __launch_bounds__(256, 3) void fused_kernel(
    const float* __restrict__ F0, const float* __restrict__ V0,
    const float* __restrict__ W1, const float* __restrict__ b1,
    const float* __restrict__ W2, const float* __restrict__ b2,
    const unsigned short* __restrict__ w1fh, const unsigned short* __restrict__ w1fl,
    const unsigned short* __restrict__ w2fh, const unsigned short* __restrict__ w2fl,
    float* __restrict__ outF, float* __restrict__ outS, float* __restrict__ outV)
{
    const int blk = blockIdx.x;
    const int j = threadIdx.x;
    const int L = j & 63, wq = j >> 6, l15 = L & 15, kq = L >> 4;

    __shared__ __align__(16) char lds[51040];
    __shared__ int idx8[GG][SV];
    __shared__ int flags0[GG], flags1[GG], predS[GG];
    __shared__ double part[NV][4];
    __shared__ double SFdS[NV];

    unsigned short* Ahi0 = (unsigned short*)lds;            // [64][72]
    unsigned short* Alo0 = Ahi0 + 64 * 72;                  // @9216
    unsigned short* Ahi1 = (unsigned short*)(lds + 18432);  // [64][72]
    unsigned short* Alo1 = Ahi1 + 64 * 72;                  // @27648
    unsigned short* Hhi  = (unsigned short*)lds;            // [32][264]
    unsigned short* Hlo  = Hhi + 32 * 264;                  // @16896
    float*  Sc      = (float*)(lds + 40960);                // 3*840 f32
    double* pooledD = (double*)lds;
    double* Dbuf    = (double*)(lds + 4096);
    double* Sd      = (double*)(lds + 6144);
    float*  Xf      = (float*)lds;                          // [20][512] rescue1

    // ---- layer-1 accumulators: acc[mt][nt], row g = mt*16+kq*4+reg (g<60 valid),
    //      col = wq*64 + nt*16 + l15.  Global row g -> batch g/20, view g%20.
    f32x4 acc[4][4];
#pragma unroll
    for (int mt = 0; mt < 4; ++mt)
#pragma unroll
        for (int nt = 0; nt < 4; ++nt) acc[mt][nt] = (f32x4){0.f, 0.f, 0.f, 0.f};

    // ---- per-thread staging descriptors (fixed across K-chunks) -------------
    const float4* srcp[4];
    int ldst[4];
    bool sval[4];
#pragma unroll
    for (int i = 0; i < 4; ++i) {
        int f = j + 256 * i;              // float4 slot in chunk [0,1024)
        int row = f >> 4, k4 = f & 15;
        sval[i] = (row < 60);
        int bi = (row >= 40) ? 2 : (row >= 20) ? 1 : 0;
        int r = row - 20 * bi;
        int batch = blk * GG + bi; if (batch > BB - 1) batch = BB - 1;
        srcp[i] = (const float4*)(F0 + ((size_t)batch * NV + r) * CC) + k4;
        ldst[i] = row * 72 + k4 * 4;
    }

    float4 rv[4];
    auto STAGE_LOAD = [&](int kc) {
#pragma unroll
        for (int i = 0; i < 4; ++i)
            if (sval[i]) rv[i] = srcp[i][kc * 16];
    };
    auto STAGE_CONVERT = [&](unsigned short* __restrict__ Ah,
                             unsigned short* __restrict__ Al) {
#pragma unroll
        for (int i = 0; i < 4; ++i) {
            ushort4v hv = {0, 0, 0, 0}, lv = {0, 0, 0, 0};
            if (sval[i]) {
                float4 x = rv[i];
                hv.x = f2bf(x.x); lv.x = f2bf(x.x - bf2f(hv.x));
                hv.y = f2bf(x.y); lv.y = f2bf(x.y - bf2f(hv.y));
                hv.z = f2bf(x.z); lv.z = f2bf(x.z - bf2f(hv.z));
                hv.w = f2bf(x.w); lv.w = f2bf(x.w - bf2f(hv.w));
            }
            *(ushort4v*)&Ah[ldst[i]] = hv;
            *(ushort4v*)&Al[ldst[i]] = lv;
        }
    };

    const uint4* Bh = (const uint4*)w1fh;
    const uint4* Bl = (const uint4*)w1fl;

    // ---- pipelined K-loop: 8 chunks of Kc=64, ONE barrier per chunk --------
    STAGE_LOAD(0);
    STAGE_CONVERT(Ahi0, Alo0);
    STAGE_LOAD(1);
    __syncthreads();

    unsigned short *Ahc = Ahi0, *Alc = Alo0, *Ahn = Ahi1, *Aln = Alo1;
    for (int kc = 0; kc < 8; ++kc) {
        if (kc < 7) {
            STAGE_CONVERT(Ahn, Aln);       // chunk kc+1 regs -> next buffer
            if (kc < 6) STAGE_LOAD(kc + 2);  // in flight across this MFMA phase
        }
#pragma unroll
        for (int ks_l = 0; ks_l < 2; ++ks_l) {
            int ks = kc * 2 + ks_l;
            uint4 bh[4], bl[4];
#pragma unroll
            for (int nt = 0; nt < 4; ++nt) {
                int bi1 = (ks * 256 + wq * 64 + nt * 16 + l15) * 4 + kq;
                bh[nt] = Bh[bi1]; bl[nt] = Bl[bi1];
            }
#pragma unroll
            for (int mt = 0; mt < 4; ++mt) {
                int off = (mt * 16 + l15) * 72 + ks_l * 32 + kq * 8;
                short8 Ah = BC8(*(const uint4*)&Ahc[off]);
                short8 Al = BC8(*(const uint4*)&Alc[off]);
#pragma unroll
                for (int nt = 0; nt < 4; ++nt) {
                    short8 Bhv = BC8(bh[nt]), Blv = BC8(bl[nt]);
                    acc[mt][nt] = MFMA16(Ah, Bhv, acc[mt][nt]);
                    acc[mt][nt] = MFMA16(Ah, Blv, acc[mt][nt]);
                    acc[mt][nt] = MFMA16(Al, Bhv, acc[mt][nt]);
                }
            }
        }
        __syncthreads();
        unsigned short* t;
        t = Ahc; Ahc = Ahn; Ahn = t;
        t = Alc; Alc = Aln; Aln = t;
    }

    // ---- layer 2: two rounds of 32 H-rows through LDS ----------------------
    // round p covers acc rows 32p..32p+31; in round 1, rows 28..30 of the H
    // buffer carry the 3 pooled rows (row 31 zeroed), giving Sc rows 60..62.
    const uint4* B2h = (const uint4*)w2fh;
    const uint4* B2l = (const uint4*)w2fl;
#pragma unroll
    for (int p = 0; p < 2; ++p) {
        __syncthreads();   // H region free (A reads / prev round reads done)
#pragma unroll
        for (int mt2 = 0; mt2 < 2; ++mt2) {
            int mt = 2 * p + mt2;
            bool skip = (p == 1 && mt2 == 1 && kq == 3);  // garbage rows 28..31
#pragma unroll
            for (int nt = 0; nt < 4; ++nt) {
                int col = wq * 64 + nt * 16 + l15;
                float bc = b1[col];
#pragma unroll
                for (int reg = 0; reg < 4; ++reg) {
                    int hb = mt2 * 16 + kq * 4 + reg;
                    float h = acc[mt][nt][reg] + bc;
                    h = (h > 0.f) ? h : 0.2f * h;
                    if (!skip) {
                        unsigned short hh = f2bf(h);
                        Hhi[hb * 264 + col] = hh;
                        Hlo[hb * 264 + col] = f2bf(h - bf2f(hh));
                    }
                }
            }
        }
        if (p == 1) {
            // pooled pre-activation = mean over the 20 view pre-activations
#pragma unroll
            for (int nt = 0; nt < 4; ++nt) {
                int col = wq * 64 + nt * 16 + l15;
                float p0 = 0.f, p1 = 0.f, p2 = 0.f;
#pragma unroll
                for (int mt = 0; mt < 4; ++mt)
#pragma unroll
                    for (int reg = 0; reg < 4; ++reg) {
                        int g = mt * 16 + kq * 4 + reg;
                        float v = acc[mt][nt][reg];
                        p0 += (g < 20) ? v : 0.f;
                        p1 += (g >= 20 && g < 40) ? v : 0.f;
                        p2 += (g >= 40 && g < 60) ? v : 0.f;
                    }
                p0 += __shfl_xor(p0, 16); p0 += __shfl_xor(p0, 32);
                p1 += __shfl_xor(p1, 16); p1 += __shfl_xor(p1, 32);
                p2 += __shfl_xor(p2, 16); p2 += __shfl_xor(p2, 32);
                if (kq < 3) {
                    float s = (kq == 0) ? p0 : (kq == 1) ? p1 : p2;
                    float h = s * (1.0f / NV) + b1[col];
                    h = (h > 0.f) ? h : 0.2f * h;
                    unsigned short hh = f2bf(h);
                    Hhi[(28 + kq) * 264 + col] = hh;
                    Hlo[(28 + kq) * 264 + col] = f2bf(h - bf2f(hh));
                } else {
                    Hhi[31 * 264 + col] = 0;
                    Hlo[31 * 264 + col] = 0;
                }
            }
        }
        __syncthreads();

        if (wq < 3) {
            f32x4 sacc[2];
            sacc[0] = (f32x4){0.f, 0.f, 0.f, 0.f};
            sacc[1] = (f32x4){0.f, 0.f, 0.f, 0.f};
            for (int ks2 = 0; ks2 < 8; ++ks2) {
                int bi2 = (ks2 * 48 + wq * 16 + l15) * 4 + kq;
                short8 Bhv = BC8(B2h[bi2]), Blv = BC8(B2l[bi2]);
#pragma unroll
                for (int tt = 0; tt < 2; ++tt) {
                    int off = (tt * 16 + l15) * 264 + ks2 * 32 + kq * 8;
                    short8 Ah2 = BC8(*(const uint4*)&Hhi[off]);
                    short8 Al2 = BC8(*(const uint4*)&Hlo[off]);
                    sacc[tt] = MFMA16(Ah2, Bhv, sacc[tt]);
                    sacc[tt] = MFMA16(Ah2, Blv, sacc[tt]);
                    sacc[tt] = MFMA16(Al2, Bhv, sacc[tt]);
                }
            }
            int cls = wq * 16 + l15;
            if (cls < NC) {
                float bc2 = b2[cls];
#pragma unroll
                for (int tt = 0; tt < 2; ++tt)
#pragma unroll
                    for (int reg = 0; reg < 4; ++reg) {
                        int lm = 32 * p + tt * 16 + kq * 4 + reg;
                        float sv = sacc[tt][reg] + bc2;
                        if (lm < 60) {
                            int bi = (lm >= 40) ? 2 : (lm >= 20) ? 1 : 0;
                            int r = lm - 20 * bi;
                            Sc[bi * 840 + r * NC + cls] = sv;
                        } else if (lm < 63) {
                            Sc[(lm - 60) * 840 + NV * NC + cls] = sv;  // pooled
                        }
                    }
            }
        }
    }
    __syncthreads();

    // ---- decisions: pred argmax (3 parallel lanes, gap-guarded) ------------
    if (j < GG) {
        const float* sp = &Sc[j * 840 + NV * NC];
        int p = 0;
        float m1 = sp[0];
        for (int c = 1; c < NC; ++c)
            if (sp[c] > m1) { m1 = sp[c]; p = c; }
        float m2 = -1e30f;
        for (int c = 0; c < NC; ++c)
            if (c != p && sp[c] > m2) m2 = sp[c];
        flags0[j] = (m1 - m2 < TAU) ? 1 : 0;
        predS[j] = p;
    }
    __syncthreads();

    for (int bi = 0; bi < GG; ++bi) {
        if (flags0[bi]) {   // rare: f64 rescore of pooled row
            int batch = blk * GG + bi; if (batch > BB - 1) batch = BB - 1;
            const float* Xb = F0 + (size_t)batch * (NV * CC);
            for (int c = j; c < CC; c += 256) {
                double s = 0.0;
                for (int r = 0; r < NV; ++r) s += (double)Xb[r * CC + c];
                pooledD[c] = s / (double)NV;
            }
            __syncthreads();
            double a = 0.0;
            for (int c = 0; c < CC; ++c) a += pooledD[c] * (double)W1[c * HH + j];
            double h = a + (double)b1[j];
            h = (h > 0.0) ? h : 0.2 * h;
            Dbuf[j] = h;
            __syncthreads();
            if (j < NC) {
                double s = 0.0;
                for (int k = 0; k < HH; ++k) s += Dbuf[k] * (double)W2[k * NC + j];
                Sd[j] = s + (double)b2[j];
            }
            __syncthreads();
            if (j == 0) {
                int p = 0;
                double m = Sd[0];
                for (int c = 1; c < NC; ++c)
                    if (Sd[c] > m) { m = Sd[c]; p = c; }
                predS[bi] = p;
            }
            __syncthreads();
        }
    }

    // ---- top-8 selection (3 parallel lanes, gap-guarded) -------------------
    if (j < GG) {
        int p = predS[j];
        float v[NV];
#pragma unroll
        for (int n = 0; n < NV; ++n) v[n] = Sc[j * 840 + n * NC + p];
        int ord[9];
        float vals[9];
        unsigned taken = 0;
#pragma unroll
        for (int s = 0; s < 9; ++s) {
            int bi = 0;
            float bv = -1e30f;
#pragma unroll
            for (int n = 0; n < NV; ++n)
                if (!((taken >> n) & 1u) && v[n] > bv) { bv = v[n]; bi = n; }
            taken |= 1u << bi;
            ord[s] = bi;
            vals[s] = bv;
        }
        int fix = 0;
#pragma unroll
        for (int s = 0; s < 8; ++s)
            if (vals[s] - vals[s + 1] < TAU) fix = 1;
        flags1[j] = fix;
        if (!fix)
#pragma unroll
            for (int s = 0; s < SV; ++s) idx8[j][s] = ord[s];
    }
    __syncthreads();

    // ---- rare: full f64 rescore of the 20 view scores at column pred -------
    // Throughput-shaped: X staged in LDS once; each thread owns hidden unit j
    // and accumulates all 20 rows concurrently (two half-passes of 10 rows to
    // cap VGPRs); W1 column value loaded once per c and reused across rows;
    // per-row wave-shuffle reduction replaces the old 8-barrier tree.
    for (int bi = 0; bi < GG; ++bi) {
        if (flags1[bi]) {
            int batch = blk * GG + bi; if (batch > BB - 1) batch = BB - 1;
            const float* Xb = F0 + (size_t)batch * (NV * CC);
            int p = predS[bi];
            for (int t = j; t < NV * CC / 4; t += 256)
                ((float4*)Xf)[t] = ((const float4*)Xb)[t];
            __syncthreads();
            const double b1d = (double)b1[j];
            const double w2jp = (double)W2[j * NC + p];
#pragma unroll
            for (int half = 0; half < 2; ++half) {
                double a[10];
#pragma unroll
                for (int r = 0; r < 10; ++r) a[r] = 0.0;
                for (int c = 0; c < CC; c += 4) {
                    double w0 = (double)W1[(c + 0) * HH + j];
                    double w1v = (double)W1[(c + 1) * HH + j];
                    double w2v = (double)W1[(c + 2) * HH + j];
                    double w3v = (double)W1[(c + 3) * HH + j];
#pragma unroll
                    for (int r = 0; r < 10; ++r) {
                        const float4 x = *(const float4*)&Xf[(half * 10 + r) * CC + c];
                        a[r] += (double)x.x * w0;
                        a[r] += (double)x.y * w1v;
                        a[r] += (double)x.z * w2v;
                        a[r] += (double)x.w * w3v;
                    }
                }
#pragma unroll
                for (int r = 0; r < 10; ++r) {
                    double h = a[r] + b1d;
                    h = (h > 0.0) ? h : 0.2 * h;
                    double val = h * w2jp;
#pragma unroll
                    for (int off = 32; off >= 1; off >>= 1)
                        val += __shfl_xor(val, off);
                    if (L == 0) part[half * 10 + r][wq] = val;
                }
            }
            __syncthreads();
            if (j < NV)
                SFdS[j] = part[j][0] + part[j][1] + part[j][2] + part[j][3]
                        + (double)b2[p];
            __syncthreads();
            if (j == 0) {
                unsigned taken = 0;
                for (int s = 0; s < SV; ++s) {
                    int bsel = 0;
                    double bv = -1e300;
                    for (int n = 0; n < NV; ++n)
                        if (!((taken >> n) & 1u) && SFdS[n] > bv) { bv = SFdS[n]; bsel = n; }
                    taken |= 1u << bsel;
                    idx8[bi][s] = bsel;
                }
            }
            __syncthreads();
        }
    }

    // ---- epilogue -----------------------------------------------------------
    for (int t = j; t < GG * NV * NC; t += 256) {
        int bi = t / 800, o = t - bi * 800;
        int batch = blk * GG + bi; if (batch > BB - 1) batch = BB - 1;
        outS[(size_t)batch * (NV * NC) + o] = Sc[bi * 840 + o];
    }

    for (int t = j; t < GG * SV * (CC / 4); t += 256) {
        int bi = t >> 10;                 // /1024
        int s = (t >> 7) & 7;
        int t4 = t & 127;
        int batch = blk * GG + bi; if (batch > BB - 1) batch = BB - 1;
        int row = idx8[bi][s];
        const float4* src = (const float4*)(F0 + ((size_t)batch * NV + row) * CC);
        float4* dst = (float4*)(outF + ((size_t)batch * SV + s) * CC);
        dst[t4] = src[t4];
    }

    if (j < GG * SV * 3) {
        int bi = j / 24, o = j - bi * 24;
        int s = o / 3, d = o - s * 3;
        int batch = blk * GG + bi; if (batch > BB - 1) batch = BB - 1;
        outV[((size_t)batch * SV + s) * 3 + d] =
            V0[((size_t)batch * NV + idx8[bi][s]) * 3 + d];
    }
}

// ---------------------------------------------------------------------------
extern "C" void kernel_launch(void* const* d_in, const int* in_sizes, int n_in,
                              void* d_out, int out_size, void* d_ws, size_t ws_size,
                              hipStream_t stream) {
    const float* F0 = (const float*)d_in[0];
    const float* V0 = (const float*)d_in[1];
    const float* W1 = (const float*)d_in[2];
    const float* b1 = (const float*)d_in[3];
    const float* W2 = (const float*)d_in[4];
    const float* b2 = (const float*)d_in[5];

    char* ws = (char*)d_ws;
    unsigned short* w1fh = (unsigned short*)ws;                   // 262144 B
    unsigned short* w1fl = (unsigned short*)(ws + 262144);        // 262144 B
    unsigned short* w2fh = (unsigned short*)(ws + 524288);        // 24576 B
    unsigned short* w2fl = (unsigned short*)(ws + 548864);        // 24576 B

    float* out = (float*)d_out;
    float* outF = out;                                // [4096,8,512]
    float* outS = out + (size_t)BB * SV * CC;         // [4096,20,40]
    float* outV = outS + (size_t)BB * NV * NC;        // [4096,8,3]

    w1pack_kernel<<<512, 256, 0, stream>>>(W1, w1fh, w1fl);
    w2pack_kernel<<<48, 256, 0, stream>>>(W2, w2fh, w2fl);
    fused_kernel<<<(BB + GG - 1) / GG, 256, 0, stream>>>(
        F0, V0, W1, b1, W2, b2, w1fh, w1fl, w2fh, w2fl, outF, outS, outV);
}